// Round 2
// baseline (312.293 us; speedup 1.0000x reference)
//
#include <hip/hip_runtime.h>

// out[b,i,h,j] = x[b,0,h,j+i] * z[b,0,h,j], zero where j+i >= W.
// B=4, H=512, W=2048, WC=16. fp32 in/out.
// Floor: 268 MB write + 32 MB read => ~48 us at 6.3 TB/s.
//
// R1: block-per-output-row. Grid = B*WC*H = 32768 blocks; block b writes
// out[blk*2048 .. blk*2048+2047] contiguously -> globally sequential write
// stream (fill-kernel-like). Reads of x/z rows are repeated across the 16
// i-planes, but those 16 blocks are 512 apart in blockIdx (512 % 8 == 0 ->
// same XCD under round-robin) and close in dispatch time -> L2-resident.

#define B_ 4
#define H_ 512
#define W_ 2048
#define WC_ 16

__global__ __launch_bounds__(256) void
space2features_kernel(const float* __restrict__ x,
                      const float* __restrict__ z,
                      float* __restrict__ out) {
    const int blk = blockIdx.x;                 // (b*WC + i)*H + h
    const int h = blk & (H_ - 1);
    const int i = (blk >> 9) & (WC_ - 1);
    const int b = blk >> 13;

    const size_t inrow = ((size_t)(b * H_ + h)) * W_;   // x/z row base
    const float* __restrict__ xr = x + inrow;
    const float* __restrict__ zr = z + inrow;
    float* __restrict__ orow = out + (size_t)blk * W_;

    const int t = threadIdx.x;

#pragma unroll
    for (int half = 0; half < 2; ++half) {
        const int j = half * 1024 + t * 4;      // [0,2048), 16B-aligned
        const float4 z4 = *(const float4*)(zr + j);

        float4 o;
        {
            // In-row clamped gather of x[j+i .. j+i+3]; mask below zeroes
            // any clamped element, so no cross-row/OOB reads ever occur.
            const int ji = j + i;
            const float x0 = xr[min(ji + 0, W_ - 1)];
            const float x1 = xr[min(ji + 1, W_ - 1)];
            const float x2 = xr[min(ji + 2, W_ - 1)];
            const float x3 = xr[min(ji + 3, W_ - 1)];
            o.x = (ji + 0 < W_) ? x0 * z4.x : 0.0f;
            o.y = (ji + 1 < W_) ? x1 * z4.y : 0.0f;
            o.z = (ji + 2 < W_) ? x2 * z4.z : 0.0f;
            o.w = (ji + 3 < W_) ? x3 * z4.w : 0.0f;
        }
        *(float4*)(orow + j) = o;
    }
}

extern "C" void kernel_launch(void* const* d_in, const int* in_sizes, int n_in,
                              void* d_out, int out_size, void* d_ws, size_t ws_size,
                              hipStream_t stream) {
    const float* x = (const float*)d_in[0];
    const float* z = (const float*)d_in[1];
    float* out = (float*)d_out;

    const int grid = B_ * WC_ * H_;   // 32768 blocks, one per output row
    space2features_kernel<<<grid, 256, 0, stream>>>(x, z, out);
}

// Round 3
// 289.997 us; speedup vs baseline: 1.0769x; 1.0769x over previous
//
#include <hip/hip_runtime.h>

// out[b,i,h,j] = x[b,0,h,j+i] * z[b,0,h,j], zero where j+i >= W.
// B=4, H=512, W=2048, WC=16. fp32 in/out.
// Floor: 268 MB write + 32 MB read => ~48 us at 6.3 TB/s.
//
// R2: sequential writes (block-per-output-row, like R1) + aligned vector
// loads (like R0). The shift i is block-uniform, so the unaligned x-window
// x[j+i..j+i+3] = rotate(A,B, i&3) where A,B are ALIGNED float4s; the
// rotate amount is uniform -> scalar branch, no per-lane select cost.

#define B_ 4
#define H_ 512
#define W_ 2048
#define WC_ 16

__global__ __launch_bounds__(256) void
space2features_kernel(const float* __restrict__ x,
                      const float* __restrict__ z,
                      float* __restrict__ out) {
    const int blk = blockIdx.x;                 // (b*WC + i)*H + h
    const int h = blk & (H_ - 1);
    const int i = (blk >> 9) & (WC_ - 1);
    const int b = blk >> 13;

    const size_t inrow = ((size_t)(b * H_ + h)) * W_;
    const float* __restrict__ xr = x + inrow;
    const float* __restrict__ zr = z + inrow;
    float* __restrict__ orow = out + (size_t)blk * W_;

    const int t = threadIdx.x;
    const int ibase = i & ~3;                   // uniform
    const int r = i & 3;                        // uniform
    const bool last_row = (b == B_ - 1) && (h == H_ - 1);  // block-uniform

#pragma unroll
    for (int half = 0; half < 2; ++half) {
        const int j = half * 1024 + t * 4;      // [0,2048), 16B-aligned
        const float4 z4 = *(const float4*)(zr + j);
        const int ji = j + i;

        float w0, w1, w2, w3;
        if (!last_row) {
            // Aligned loads; may read <=15 floats into the next row — those
            // elements are used only where j+i+k >= W, which is masked to 0.
            const float4 A = *(const float4*)(xr + j + ibase);
            const float4 Bv = *(const float4*)(xr + j + ibase + 4);
            switch (r) {                        // uniform -> scalar branch
                case 0:  w0 = A.x; w1 = A.y; w2 = A.z; w3 = A.w; break;
                case 1:  w0 = A.y; w1 = A.z; w2 = A.w; w3 = Bv.x; break;
                case 2:  w0 = A.z; w1 = A.w; w2 = Bv.x; w3 = Bv.y; break;
                default: w0 = A.w; w1 = Bv.x; w2 = Bv.y; w3 = Bv.z; break;
            }
        } else {
            // Absolute last input row: clamp indices inside the row.
            w0 = xr[min(ji + 0, W_ - 1)];
            w1 = xr[min(ji + 1, W_ - 1)];
            w2 = xr[min(ji + 2, W_ - 1)];
            w3 = xr[min(ji + 3, W_ - 1)];
        }

        float4 o;
        o.x = (ji + 0 < W_) ? w0 * z4.x : 0.0f;
        o.y = (ji + 1 < W_) ? w1 * z4.y : 0.0f;
        o.z = (ji + 2 < W_) ? w2 * z4.z : 0.0f;
        o.w = (ji + 3 < W_) ? w3 * z4.w : 0.0f;
        *(float4*)(orow + j) = o;
    }
}

extern "C" void kernel_launch(void* const* d_in, const int* in_sizes, int n_in,
                              void* d_out, int out_size, void* d_ws, size_t ws_size,
                              hipStream_t stream) {
    const float* x = (const float*)d_in[0];
    const float* z = (const float*)d_in[1];
    float* out = (float*)d_out;

    const int grid = B_ * WC_ * H_;   // 32768 blocks, one per output row
    space2features_kernel<<<grid, 256, 0, stream>>>(x, z, out);
}